// Round 5
// baseline (127.874 us; speedup 1.0000x reference)
//
#include <hip/hip_runtime.h>
#include <hip/hip_bf16.h>

#define NN 8192
#define DD 128
#define BM 16
#define JS 8            // j-slices (K-split of the S@h reduction)
#define RPB 128         // output rows per block
#define JSLICE 1024     // j columns per block
#define KBLK 128        // j columns per staged chunk
#define LSTR 272        // LDS bytes per row: 128*2 + 16 pad (conflict-free)

typedef __attribute__((ext_vector_type(4))) float f32x4;
typedef __attribute__((ext_vector_type(8))) short bf16x8;

__device__ __forceinline__ unsigned short f2bf(float x) {
    unsigned u = __float_as_uint(x);
    u += 0x7fffu + ((u >> 16) & 1u);   // round-to-nearest-even
    return (unsigned short)(u >> 16);
}

// ---------------------------------------------------------------------------
// Kernel A: hT[n][j] = bf16( B[n] + sum_k z[j][k] * W[k][n] ), plain layout.
// ---------------------------------------------------------------------------
__global__ void __launch_bounds__(256) h_transform(
    const float* __restrict__ z, const float* __restrict__ W,
    const float* __restrict__ Bv, unsigned short* __restrict__ hT) {
    __shared__ float zs[BM * DD];
    __shared__ float wt[DD * 132];
    const int t = threadIdx.x;
    const int j0 = blockIdx.x * BM;

    {
        const f32x4* zsrc = (const f32x4*)(z + (size_t)j0 * DD);
        f32x4* zdst = (f32x4*)zs;
        zdst[t] = zsrc[t];
        zdst[t + 256] = zsrc[t + 256];
    }
    for (int q = t; q < DD * 32; q += 256) {
        int k = q >> 5;
        int n0 = (q & 31) << 2;
        f32x4 wv = *(const f32x4*)(W + k * DD + n0);
        wt[(n0 + 0) * 132 + k] = wv[0];
        wt[(n0 + 1) * 132 + k] = wv[1];
        wt[(n0 + 2) * 132 + k] = wv[2];
        wt[(n0 + 3) * 132 + k] = wv[3];
    }
    __syncthreads();

    const int n = t >> 1;
    const int ja = (t & 1) << 3;
    float acc[8];
    float bn = Bv[n];
#pragma unroll
    for (int e = 0; e < 8; e++) acc[e] = bn;

#pragma unroll 8
    for (int k4 = 0; k4 < 32; ++k4) {
        f32x4 wv = *(const f32x4*)&wt[n * 132 + (k4 << 2)];
#pragma unroll
        for (int e = 0; e < 8; e++) {
            f32x4 zv = *(const f32x4*)&zs[(ja + e) * DD + (k4 << 2)];
            acc[e] += zv[0] * wv[0] + zv[1] * wv[1] + zv[2] * wv[2] + zv[3] * wv[3];
        }
    }

    const int j = j0 + ja;
    unsigned short* dst = hT + (size_t)n * NN + j;
    uint4 uv;
    uv.x = (unsigned)f2bf(acc[0]) | ((unsigned)f2bf(acc[1]) << 16);
    uv.y = (unsigned)f2bf(acc[2]) | ((unsigned)f2bf(acc[3]) << 16);
    uv.z = (unsigned)f2bf(acc[4]) | ((unsigned)f2bf(acc[5]) << 16);
    uv.w = (unsigned)f2bf(acc[6]) | ((unsigned)f2bf(acc[7]) << 16);
    *(uint4*)dst = uv;
}

// ---------------------------------------------------------------------------
// Kernel B: fused S + S@h. HBM-friendly: dist loaded in CONTIGUOUS 512 B
// runs per row (2 rows per load instruction), S computed in-register and
// redistributed to MFMA fragment layout via LDS. hT chunk staged in LDS.
// 2 blocks/CU (69.6 KB LDS, <=128 VGPR) -> stage/compute overlap across
// blocks. Fragment offsets byte-identical to the validated round-4 kernel.
// Grid: 64 rowblocks x 8 jslices; block 512 thr = 8 waves x 16 rows.
// ---------------------------------------------------------------------------
__global__ void __launch_bounds__(512, 4) fused_interact(
    const float* __restrict__ dist, const unsigned short* __restrict__ hT,
    const float* __restrict__ mu, const float* __restrict__ sigma,
    float* __restrict__ part) {
    __shared__ char s_lds[RPB * LSTR];   // S tile  [128 r][128 k] bf16 + pad
    __shared__ char h_lds[DD * LSTR];    // hT tile [128 n][128 j] bf16 + pad

    const int t = threadIdx.x;
    const int w = t >> 6;
    const int l = t & 63;
    const int rb = (int)blockIdx.x >> 3;
    const int js = (int)blockIdx.x & 7;
    const int r0 = rb * RPB;

    // staging maps
    const int dr = t >> 5;               // 0..15 (+16*p): dist row
    const int dc = (t & 31) << 2;        // dist col (elements), 16B/lane
    const int hn = t >> 4;               // 0..31 (+32*q): hT n-row
    const int hc = (t & 15) << 3;        // hT col (elements), 16B/lane

    // fragment read offsets (validated layout from round 4)
    const int fr = l & 15;
    const int fq = l >> 4;               // 0..3
    const int a_base = (w * 16 + fr) * LSTR + fq * 16;   // + ks*64
    const int b_base = fr * LSTR + fq * 16;              // + f*16*LSTR + ks*64

    const float inv_mu = 1.0f / mu[0];
    const float sg = sigma[0];
    const float ninv2s2 = -1.0f / (2.0f * sg * sg);

    f32x4 acc[8];
#pragma unroll
    for (int f = 0; f < 8; ++f) acc[f] = (f32x4){0.f, 0.f, 0.f, 0.f};

#pragma unroll 1
    for (int chunk = 0; chunk < JSLICE / KBLK; ++chunk) {
        const int jc = js * JSLICE + chunk * KBLK;

        // issue all global loads first (contiguous runs; latency overlaps
        // the pre-barrier wait and the co-resident block's compute)
        f32x4 dv[8];
        uint4 hv[4];
#pragma unroll
        for (int p = 0; p < 8; ++p)
            dv[p] = *(const f32x4*)(dist + (size_t)(r0 + p * 16 + dr) * NN +
                                    jc + dc);
#pragma unroll
        for (int q = 0; q < 4; ++q)
            hv[q] = *(const uint4*)(hT + (size_t)(hn + q * 32) * NN + jc + hc);

        __syncthreads();   // all waves done reading previous tiles

        // hT tile -> LDS
#pragma unroll
        for (int q = 0; q < 4; ++q)
            *(uint4*)(h_lds + (hn + q * 32) * LSTR + (hc << 1)) = hv[q];

        // S = sens(dist) -> bf16 -> LDS (fragment-ready layout)
#pragma unroll
        for (int p = 0; p < 8; ++p) {
            const int rloc = p * 16 + dr;
            const int rg = r0 + rloc;
            unsigned short h[4];
#pragma unroll
            for (int e = 0; e < 4; ++e) {
                float d = dv[p][e];
                float q = __builtin_amdgcn_rcpf(d) - inv_mu;
                float s = __expf(q * q * ninv2s2);
                bool keep = (d < 0.5f) & ((jc + dc + e) != rg);
                h[e] = f2bf(keep ? s : 0.0f);
            }
            uint2 u;
            u.x = (unsigned)h[0] | ((unsigned)h[1] << 16);
            u.y = (unsigned)h[2] | ((unsigned)h[3] << 16);
            *(uint2*)(s_lds + rloc * LSTR + (dc << 1)) = u;
        }

        __syncthreads();   // tiles ready

        // MFMA: wave w computes its 16 rows x 128 n for this K=128 chunk
#pragma unroll
        for (int ks = 0; ks < 4; ++ks) {
            bf16x8 a = *(const bf16x8*)(s_lds + a_base + ks * 64);
#pragma unroll
            for (int f = 0; f < 8; ++f) {
                bf16x8 b =
                    *(const bf16x8*)(h_lds + b_base + f * (16 * LSTR) + ks * 64);
                acc[f] = __builtin_amdgcn_mfma_f32_16x16x32_bf16(a, b, acc[f],
                                                                 0, 0, 0);
            }
        }
    }

    // epilogue (validated C-layout: row = fq*4+rr, col = f*16+fr)
    float* po = part + (size_t)js * (NN * DD);
    const int orow = r0 + w * 16 + (fq << 2);
#pragma unroll
    for (int f = 0; f < 8; ++f)
#pragma unroll
        for (int rr = 0; rr < 4; ++rr)
            po[(size_t)(orow + rr) * DD + f * 16 + fr] = acc[f][rr];
}

// ---------------------------------------------------------------------------
// Kernel C: sum the 8 K-split partials into out.
// ---------------------------------------------------------------------------
__global__ void __launch_bounds__(256) reduce_part(
    const float* __restrict__ part, float* __restrict__ outp) {
    const size_t idx = ((size_t)blockIdx.x * 256 + threadIdx.x) << 2;
    f32x4 s = *(const f32x4*)(part + idx);
#pragma unroll
    for (int ksp = 1; ksp < JS; ++ksp)
        s += *(const f32x4*)(part + (size_t)ksp * (NN * DD) + idx);
    *(f32x4*)(outp + idx) = s;
}

extern "C" void kernel_launch(void* const* d_in, const int* in_sizes, int n_in,
                              void* d_out, int out_size, void* d_ws, size_t ws_size,
                              hipStream_t stream) {
    const float* z = (const float*)d_in[0];
    const float* dist = (const float*)d_in[1];
    const float* W = (const float*)d_in[2];
    const float* Bv = (const float*)d_in[3];
    const float* mu = (const float*)d_in[4];
    const float* sigma = (const float*)d_in[5];
    float* out = (float*)d_out;

    unsigned short* hT = (unsigned short*)d_ws;                 // 2 MB
    const size_t hT_bytes = (size_t)DD * NN * 2;
    float* part = (float*)((char*)d_ws + hT_bytes);             // 8 x 4 MB

    h_transform<<<NN / BM, 256, 0, stream>>>(z, W, Bv, hT);
    fused_interact<<<(NN / RPB) * JS, 512, 0, stream>>>(dist, hT, mu, sigma,
                                                        part);
    reduce_part<<<(NN * DD) / 1024, 256, 0, stream>>>(part, out);
}